// Round 18
// baseline (100.266 us; speedup 1.0000x reference)
//
#include <hip/hip_runtime.h>

#define TREES 32
#define NIPT  511
#define VLEAF 5000

typedef __bf16 bf16_t;
typedef bf16_t bf16x4 __attribute__((ext_vector_type(4)));
typedef bf16_t bf16x8 __attribute__((ext_vector_type(8)));
typedef float  f32x4  __attribute__((ext_vector_type(4)));

__device__ __forceinline__ float sigf(float x) { return 1.0f/(1.0f+__expf(-x)); }
__device__ __forceinline__ float tanh_fast(float x) { return 2.0f/(1.0f+__expf(-2.0f*x)) - 1.0f; }

__device__ __forceinline__ bf16x8 to_bf16x8(const float* p) {
  float4 a = *(const float4*)p;
  float4 b = *(const float4*)(p+4);
  bf16x8 r;
  r[0]=(bf16_t)a.x; r[1]=(bf16_t)a.y; r[2]=(bf16_t)a.z; r[3]=(bf16_t)a.w;
  r[4]=(bf16_t)b.x; r[5]=(bf16_t)b.y; r[6]=(bf16_t)b.z; r[7]=(bf16_t)b.w;
  return r;
}
__device__ __forceinline__ bf16x8 zero_bf16x8() {
  bf16x8 r;
  #pragma unroll
  for (int i=0;i<8;++i) r[i]=(bf16_t)0.0f;
  return r;
}
__device__ __forceinline__ bf16x8 ldsB(const char* lds, int col, int kb, int rowb) {
  return *(const bf16x8*)(lds + col*rowb + kb);
}

// ---- per-wave U fragments (fp32 source; L2-backed remat accepted — R9/R14-proven)
__device__ __forceinline__ void load_breg(const float* __restrict__ U_iou,
                                          const float* __restrict__ U_f,
                                          int cs, int lg, int col0, bf16x8 breg[8][4]) {
  #pragma unroll
  for (int gs=0; gs<8; ++gs) {
    int col = (gs>>1)*128 + cs*32 + (gs&1)*16 + col0;
    const float* src; int ld;
    if (col < 384) { src = U_iou + col; ld = 384; }
    else           { src = U_f + (col-384); ld = 128; }
    #pragma unroll
    for (int ks=0; ks<4; ++ks) {
      #pragma unroll
      for (int i=0;i<8;++i) breg[gs][ks][i] = (bf16_t)src[(ks*32 + lg*8 + i)*ld];
    }
  }
}

__device__ __forceinline__ void mfma8(const bf16x8 a[4], const bf16x8 breg[8][4], f32x4 acc[8]) {
  #pragma unroll
  for (int ks=0; ks<4; ++ks) {
    #pragma unroll
    for (int gs=0; gs<8; ++gs)
      acc[gs] = __builtin_amdgcn_mfma_f32_16x16x32_bf16(a[ks], breg[gs][ks], acc[gs], 0,0,0);
  }
}

// LSTM combine: acc gs = {i:0,1 | o:2,3 | u:4,5 | f:6,7}, rows 2pp,2pp+1 = children L,R
__device__ __forceinline__ void lstm_epi(const f32x4 acc[8], const bf16x4 w4[2][2],
                                         const float2 cp[2][2],
                                         float hn[2][2], float cn[2][2]) {
  #pragma unroll
  for (int pp=0; pp<2; ++pp) {
    #pragma unroll
    for (int s2=0; s2<2; ++s2) {
      float iv = acc[s2][2*pp]   + acc[s2][2*pp+1]   + (float)w4[pp][s2][0];
      float ov = acc[2+s2][2*pp] + acc[2+s2][2*pp+1] + (float)w4[pp][s2][1];
      float uv = acc[4+s2][2*pp] + acc[4+s2][2*pp+1] + (float)w4[pp][s2][2];
      float wf = (float)w4[pp][s2][3];
      float fl = sigf(acc[6+s2][2*pp]   + wf);
      float fr = sigf(acc[6+s2][2*pp+1] + wf);
      float cf = fl*cp[pp][s2].x + fr*cp[pp][s2].y;
      float c  = sigf(iv)*tanh_fast(uv) + cf;
      cn[pp][s2] = c;
      hn[pp][s2] = sigf(ov)*tanh_fast(c);
    }
  }
}

// ---- LINEAR-READ transpose staging (all 1024 threads, coalesced float4 reads) ----
// [W_iou(128x384) | W_f(128x128)] fp32 row-major -> LDS N-major [512 cols][128 k], stride 264B
__device__ __forceinline__ void stage_WU_lin(const float* __restrict__ Wa,
                                             const float* __restrict__ Wb,
                                             char* lds, int tid) {
  #pragma unroll
  for (int t=0; t<12; ++t) {                      // Wa: 12288 float4
    int q = tid + t*1024;
    int k = q / 96, c4 = (q - k*96)*4;
    float4 v = *(const float4*)(Wa + k*384 + c4);
    *(bf16_t*)(lds + (c4+0)*264 + k*2) = (bf16_t)v.x;
    *(bf16_t*)(lds + (c4+1)*264 + k*2) = (bf16_t)v.y;
    *(bf16_t*)(lds + (c4+2)*264 + k*2) = (bf16_t)v.z;
    *(bf16_t*)(lds + (c4+3)*264 + k*2) = (bf16_t)v.w;
  }
  #pragma unroll
  for (int t=0; t<4; ++t) {                       // Wb: 4096 float4
    int q = tid + t*1024;
    int k = q / 32, c4 = (q - k*32)*4;
    float4 v = *(const float4*)(Wb + k*128 + c4);
    *(bf16_t*)(lds + (384+c4+0)*264 + k*2) = (bf16_t)v.x;
    *(bf16_t*)(lds + (384+c4+1)*264 + k*2) = (bf16_t)v.y;
    *(bf16_t*)(lds + (384+c4+2)*264 + k*2) = (bf16_t)v.z;
    *(bf16_t*)(lds + (384+c4+3)*264 + k*2) = (bf16_t)v.w;
  }
}
// W_leaf[3][64][512] fp32 -> LDS [384 cols=[gi|gg|go]][192 k block-diag], stride 392B
__device__ __forceinline__ void stage_WL_lin(const float* __restrict__ W_leaf,
                                             char* lds, int tid) {
  #pragma unroll
  for (int t=0; t<24; ++t) {                      // 24576 float4 (gf quarter skipped)
    int q = tid + t*1024;
    int v4 = q*4;
    int kk = v4 >> 15;                            // vocab block
    int rem = v4 & 32767;
    int k = kk*64 + (rem >> 9);                   // 0..191
    int c = rem & 511;                            // source gate column base
    if (c < 128 || c >= 256) {                    // keep gi, gg, go; skip gf
      int dcol = (c < 128) ? c : c - 128;
      float4 v = *(const float4*)(W_leaf + (size_t)v4);
      *(bf16_t*)(lds + (dcol+0)*392 + k*2) = (bf16_t)v.x;
      *(bf16_t*)(lds + (dcol+1)*392 + k*2) = (bf16_t)v.y;
      *(bf16_t*)(lds + (dcol+2)*392 + k*2) = (bf16_t)v.z;
      *(bf16_t*)(lds + (dcol+3)*392 + k*2) = (bf16_t)v.w;
    }
  }
}

// =================== kernel 1: leaf (blocks 0-127, 128 each) | wx_table (128-132)
__global__ __launch_bounds__(1024) void k_leaf_table(
    const int* __restrict__ features, const int* __restrict__ vocabs,
    const float* __restrict__ emb_res, const float* __restrict__ emb_leaf,
    const float* __restrict__ W_iou, const float* __restrict__ b_iou,
    const float* __restrict__ W_f, const float* __restrict__ b_f,
    const float* __restrict__ W_leaf, const float* __restrict__ b_leaf,
    bf16_t* __restrict__ wxt, bf16_t* __restrict__ hg, float* __restrict__ c2)
{
  __shared__ __align__(16) char Blds[150528];
  const int tid = threadIdx.x, wave = tid>>6, lane = tid&63;
  const int rg = wave>>2, cs = wave&3, lg = lane>>4, col0 = lane&15;

  if (blockIdx.x < 128) {
    // ===== leaf: block-diag K=192 GEMM, N=384 [gi|gg|go]; 128 leaves/block
    // prefetch A operands (independent of staging) for both mtiles
    int kkA_[2]; bf16x8 alo_[2], ahi_[2];
    #pragma unroll
    for (int mi=0; mi<2; ++mi) {
      int mt = rg + mi*4;
      int rA = (int)blockIdx.x*128 + mt*16 + (lane&15);
      int treeA = rA>>9, loA = rA&511;
      int nodeA = treeA*1023 + 511 + loA;
      int kkA = vocabs[nodeA]-1;
      int featA = features[nodeA];
      const float* xp = emb_leaf + ((size_t)kkA*VLEAF + featA)*64;
      kkA_[mi] = kkA;
      alo_[mi] = to_bf16x8(xp + lg*8);
      ahi_[mi] = to_bf16x8(xp + 32 + lg*8);
    }

    stage_WL_lin(W_leaf, Blds, tid);
    __syncthreads();

    #pragma unroll
    for (int mi=0; mi<2; ++mi) {
      int mt = rg + mi*4;
      const int base = (int)blockIdx.x*128 + mt*16;

      f32x4 acc[6];
      #pragma unroll
      for (int j=0;j<6;++j) acc[j] = (f32x4){0.f,0.f,0.f,0.f};
      #pragma unroll
      for (int ks=0; ks<6; ++ks) {
        bf16x8 a = (ks == 2*kkA_[mi])   ? alo_[mi]
                 : (ks == 2*kkA_[mi]+1) ? ahi_[mi] : zero_bf16x8();
        #pragma unroll
        for (int g=0; g<3; ++g) {
          #pragma unroll
          for (int s=0; s<2; ++s) {
            bf16x8 b = ldsB(Blds, g*128 + cs*32 + s*16 + col0, ks*64 + lg*16, 392);
            acc[g*2+s] = __builtin_amdgcn_mfma_f32_16x16x32_bf16(a, b, acc[g*2+s], 0,0,0);
          }
        }
      }
      #pragma unroll
      for (int r=0; r<4; ++r) {
        int L = base + lg*4 + r;
        int tree = L>>9, lo = L&511;
        int l = 511 + lo;
        int node = tree*1023 + l;
        int kk = vocabs[node]-1;
        const float* bl = b_leaf + kk*512;
        int pl = l - 1;
        size_t c2b = ((size_t)tree*511 + (pl>>1))*256;
        #pragma unroll
        for (int s=0; s<2; ++s) {
          int cc = cs*32 + s*16 + col0;
          float gi = acc[s][r]   + bl[cc];
          float gg = acc[2+s][r] + bl[256+cc];
          float go = acc[4+s][r] + bl[384+cc];
          float ck = sigf(gi)*tanh_fast(gg);
          float hk = sigf(go)*tanh_fast(ck);
          c2[c2b + cc*2 + (pl&1)] = ck;
          hg[(size_t)node*128+cc] = (bf16_t)hk;
        }
      }
    }
  } else {
    // ===== wx_table: table[row] = bf16(emb_res[row]@[W_iou|W_f]+bias), 128 rows/block
    const int tb = (int)blockIdx.x - 128;        // 0..4
    // prefetch A rows (independent of staging)
    bf16x8 at_[2][4];
    #pragma unroll
    for (int mi=0; mi<2; ++mi) {
      int mt = rg + mi*4;
      int rowA = tb*128 + mt*16 + (lane&15);
      if (rowA >= 600) rowA = 599;
      const float* ep = emb_res + (size_t)rowA*128 + lg*8;
      #pragma unroll
      for (int ks=0; ks<4; ++ks) at_[mi][ks] = to_bf16x8(ep + ks*32);
    }

    stage_WU_lin(W_iou, W_f, Blds, tid);
    __syncthreads();

    #pragma unroll
    for (int mi=0; mi<2; ++mi) {
      int mt = rg + mi*4;
      int row0 = tb*128 + mt*16;

      f32x4 acc[8];
      #pragma unroll
      for (int j=0;j<8;++j) acc[j] = (f32x4){0.f,0.f,0.f,0.f};
      #pragma unroll
      for (int ks=0; ks<4; ++ks) {
        #pragma unroll
        for (int j=0; j<8; ++j) {
          bf16x8 b = ldsB(Blds, cs*128 + j*16 + col0, ks*64 + lg*16, 264);
          acc[j] = __builtin_amdgcn_mfma_f32_16x16x32_bf16(at_[mi][ks], b, acc[j], 0,0,0);
        }
      }
      #pragma unroll
      for (int j=0; j<8; ++j) {
        int hcol = j*16 + col0;
        int c = cs*128 + hcol;
        float bias = (c < 384) ? b_iou[c] : b_f[c-384];
        #pragma unroll
        for (int r=0; r<4; ++r) {
          int ci = row0 + lg*4 + r;
          if (ci >= 600) ci = 599;               // duplicate writes carry identical data
          wxt[(size_t)ci*512 + hcol*4 + cs] = (bf16_t)(acc[j][r] + bias);
        }
      }
    }
  }
}

// =================== kernel 2: levels 1..6 (R14 structure; wx via feat->table) =
__global__ __launch_bounds__(512, 2) void k_levels(
    const float* __restrict__ U_iou, const float* __restrict__ U_f,
    const int* __restrict__ features, const bf16_t* __restrict__ wxt,
    bf16_t* __restrict__ hg, float* __restrict__ c2)
{
  __shared__ __align__(16) bf16_t st_h[48][136];
  __shared__ float st_c[48][132];
  const int tid = threadIdx.x, wave = tid>>6, lane = tid&63;
  const int rg = wave>>2, cs = wave&3, lg = lane>>4, col0 = lane&15;
  const int blk = blockIdx.x, tree = blk>>3, b8 = blk&7;

  bf16x8 breg[8][4];
  load_breg(U_iou, U_f, cs, lg, col0, breg);

  // ---------- n=1: A = leaf h (global), c = c2 (global); out -> st rows 0..31
  #pragma unroll
  for (int mi=0; mi<2; ++mi) {
    const int mt = rg + mi*2;
    int rr = lane&15;
    int fp = blk*32 + mt*8 + (rr>>1);          // flat order-1 parent
    int loA = fp & 255;
    int chA = tree*1023 + 2*(255+loA) + 1 + (rr&1);
    const bf16_t* hp = hg + (size_t)chA*128 + lg*8;
    bf16x8 a[4];
    #pragma unroll
    for (int ks=0; ks<4; ++ks) a[ks] = *(const bf16x8*)(hp + ks*32);

    bf16x4 w4[2][2]; float2 cp[2][2]; int pib[2];
    #pragma unroll
    for (int pp=0; pp<2; ++pp) {
      int pj = mt*8 + lg*2 + pp;
      pib[pp] = pj;
      int plocal = 255 + b8*32 + pj;
      int feat = features[tree*1023 + plocal];
      size_t ci = (size_t)tree*511 + plocal;
      #pragma unroll
      for (int s2=0; s2<2; ++s2) {
        int hcol = cs*32 + s2*16 + col0;
        w4[pp][s2] = *(const bf16x4*)(wxt + (size_t)feat*512 + hcol*4);
        cp[pp][s2] = *(const float2*)(c2 + ci*256 + hcol*2);
      }
    }

    f32x4 acc[8];
    #pragma unroll
    for (int gs=0; gs<8; ++gs) acc[gs] = (f32x4){0.f,0.f,0.f,0.f};
    mfma8(a, breg, acc);
    float hn[2][2], cn[2][2];
    lstm_epi(acc, w4, cp, hn, cn);
    #pragma unroll
    for (int pp=0; pp<2; ++pp) {
      #pragma unroll
      for (int s2=0; s2<2; ++s2) {
        int hcol = cs*32 + s2*16 + col0;
        st_c[pib[pp]][hcol] = cn[pp][s2];
        st_h[pib[pp]][hcol] = (bf16_t)hn[pp][s2];
      }
    }
  }
  __syncthreads();

  // ---------- n=2: children = st rows 0..31; out -> st rows 32..47
  {
    const int mt2 = rg;
    int rr = lane&15;
    int crow = mt2*16 + rr;
    bf16x8 a[4];
    #pragma unroll
    for (int ks=0; ks<4; ++ks)
      a[ks] = *(const bf16x8*)(&st_h[crow][ks*32 + lg*8]);

    bf16x4 w4[2][2]; float2 cp[2][2]; int pnode[2];
    #pragma unroll
    for (int pp=0; pp<2; ++pp) {
      int pj = mt2*8 + lg*2 + pp;                // [0,16)
      pnode[pp] = 32 + pj;
      int f2 = blk*16 + pj;
      int tr2 = f2>>7, lo = f2&127;
      int plocal = 127+lo;
      int feat = features[tr2*1023 + plocal];
      #pragma unroll
      for (int s2=0; s2<2; ++s2) {
        int hcol = cs*32 + s2*16 + col0;
        w4[pp][s2] = *(const bf16x4*)(wxt + (size_t)feat*512 + hcol*4);
        cp[pp][s2] = make_float2(st_c[2*pj][hcol], st_c[2*pj+1][hcol]);
      }
    }

    f32x4 acc[8];
    #pragma unroll
    for (int gs=0; gs<8; ++gs) acc[gs] = (f32x4){0.f,0.f,0.f,0.f};
    mfma8(a, breg, acc);
    float hn[2][2], cn[2][2];
    lstm_epi(acc, w4, cp, hn, cn);
    #pragma unroll
    for (int pp=0; pp<2; ++pp) {
      #pragma unroll
      for (int s2=0; s2<2; ++s2) {
        int hcol = cs*32 + s2*16 + col0;
        st_c[pnode[pp]][hcol] = cn[pp][s2];
        st_h[pnode[pp]][hcol] = (bf16_t)hn[pp][s2];
      }
    }
  }
  __syncthreads();

  // ---------- n=3..6: rowgroup 0 only; st->st (li<3) or st->global (li=3)
  const int Pn_[4]   = {8, 4, 2, 1};
  const int cb_[4]   = {32, 0, 8, 12};     // child st row base
  const int ob_[4]   = {0, 8, 12, 0};      // out st row base (li<3)
  const int base_[4] = {63, 31, 15, 7};    // parent plocal base
  const int mul_[4]  = {8, 4, 2, 1};       // parents per block
  #pragma unroll
  for (int li=0; li<4; ++li) {
    if (rg == 0) {
      const int Pn = Pn_[li];
      int rr = lane&15;
      int r2 = (rr < 2*Pn) ? rr : 0;
      bf16x8 a[4];
      #pragma unroll
      for (int ks=0; ks<4; ++ks)
        a[ks] = *(const bf16x8*)(&st_h[cb_[li] + r2][ks*32 + lg*8]);

      bf16x4 w4[2][2]; float2 cp[2][2]; int pj[2], plocal[2];
      #pragma unroll
      for (int pp=0; pp<2; ++pp) {
        pj[pp] = lg*2 + pp;
        plocal[pp] = base_[li] + b8*mul_[li] + pj[pp];
        int feat = features[tree*1023 + plocal[pp]];
        int cr0 = cb_[li] + 2*pj[pp];
        #pragma unroll
        for (int s2=0; s2<2; ++s2) {
          int hcol = cs*32 + s2*16 + col0;
          w4[pp][s2] = *(const bf16x4*)(wxt + (size_t)feat*512 + hcol*4);
          cp[pp][s2] = make_float2(st_c[cr0][hcol], st_c[cr0+1][hcol]);
        }
      }

      f32x4 acc[8];
      #pragma unroll
      for (int gs=0; gs<8; ++gs) acc[gs] = (f32x4){0.f,0.f,0.f,0.f};
      mfma8(a, breg, acc);
      float hn[2][2], cn[2][2];
      lstm_epi(acc, w4, cp, hn, cn);
      #pragma unroll
      for (int pp=0; pp<2; ++pp) {
        if (pj[pp] < Pn) {
          #pragma unroll
          for (int s2=0; s2<2; ++s2) {
            int hcol = cs*32 + s2*16 + col0;
            if (li < 3) {
              st_c[ob_[li] + pj[pp]][hcol] = cn[pp][s2];
              st_h[ob_[li] + pj[pp]][hcol] = (bf16_t)hn[pp][s2];
            } else {
              // order-6 -> global (plocal = 7 + b8)
              int pl = plocal[pp] - 1;
              c2[((size_t)tree*511 + (pl>>1))*256 + hcol*2 + (pl&1)] = cn[pp][s2];
              hg[((size_t)tree*1023 + plocal[pp])*128 + hcol] = (bf16_t)hn[pp][s2];
            }
          }
        }
      }
    }
    __syncthreads();
  }
}

// =================== kernel 3: levels 7..9 + root head (feat->table wx) =======
__global__ __launch_bounds__(512, 2) void k_tail(
    const float* __restrict__ U_iou, const float* __restrict__ U_f,
    const int* __restrict__ features, const bf16_t* __restrict__ wxt,
    bf16_t* __restrict__ hg, float* __restrict__ c2,
    const float* __restrict__ Wm, const float* __restrict__ bm,
    const float* __restrict__ Wv, const float* __restrict__ bv,
    const float* __restrict__ eps, float* __restrict__ out)
{
  __shared__ float hs[128];
  const int tid = threadIdx.x, wave = tid>>6, lane = tid&63;
  const int rg = wave>>2, cs = wave&3, lg = lane>>4, col0 = lane&15;
  const int tree = blockIdx.x;

  bf16x8 breg[8][4];
  load_breg(U_iou, U_f, cs, lg, col0, breg);

  const int Pn_[3]  = {4, 2, 1};
  const int chb_[3] = {7, 3, 1};     // child local base
  const int pb_[3]  = {3, 1, 0};     // parent local base
  #pragma unroll
  for (int li=0; li<3; ++li) {
    if (rg == 0) {
      const int Pn = Pn_[li];
      int rr = lane&15;
      int r2 = (rr < 2*Pn) ? rr : 0;
      const bf16_t* hp = hg + ((size_t)tree*1023 + chb_[li] + r2)*128 + lg*8;
      bf16x8 a[4];
      #pragma unroll
      for (int ks=0; ks<4; ++ks) a[ks] = *(const bf16x8*)(hp + ks*32);

      bf16x4 w4[2][2]; float2 cp[2][2]; int pj[2], plocal[2];
      #pragma unroll
      for (int pp=0; pp<2; ++pp) {
        pj[pp] = lg*2 + pp;
        plocal[pp] = pb_[li] + pj[pp];
        int pl_c = (plocal[pp] < 7) ? plocal[pp] : 6;
        int feat = features[tree*1023 + pl_c];
        size_t ci = (size_t)tree*511 + pl_c;
        #pragma unroll
        for (int s2=0; s2<2; ++s2) {
          int hcol = cs*32 + s2*16 + col0;
          w4[pp][s2] = *(const bf16x4*)(wxt + (size_t)feat*512 + hcol*4);
          cp[pp][s2] = *(const float2*)(c2 + ci*256 + hcol*2);
        }
      }

      f32x4 acc[8];
      #pragma unroll
      for (int gs=0; gs<8; ++gs) acc[gs] = (f32x4){0.f,0.f,0.f,0.f};
      mfma8(a, breg, acc);
      float hn[2][2], cn[2][2];
      lstm_epi(acc, w4, cp, hn, cn);
      #pragma unroll
      for (int pp=0; pp<2; ++pp) {
        if (pj[pp] < Pn) {
          #pragma unroll
          for (int s2=0; s2<2; ++s2) {
            int hcol = cs*32 + s2*16 + col0;
            if (li < 2) {
              int pl = plocal[pp] - 1;
              c2[((size_t)tree*511 + (pl>>1))*256 + hcol*2 + (pl&1)] = cn[pp][s2];
              hg[((size_t)tree*1023 + plocal[pp])*128 + hcol] = (bf16_t)hn[pp][s2];
            } else {
              hs[hcol] = hn[pp][s2];       // root h -> LDS only
            }
          }
        }
      }
    }
    __threadfence_block();
    __syncthreads();
  }

  // fused root head
  if (tid < 64) {
    const int j = tid;
    float am = 0.f, av = 0.f;
    #pragma unroll 4
    for (int i=0;i<128;++i) {
      float hv = hs[i];
      am += hv*Wm[i*64+j];
      av += hv*Wv[i*64+j];
    }
    float zm = am + bm[j];
    float zv = av + bv[j];
    int idx = tree*64 + j;
    out[idx]        = zm + eps[idx]*__expf(0.5f*zv);
    out[2048 + idx] = zm;
    out[4096 + idx] = zv;
  }
}

// =================== host launcher ============================================
extern "C" void kernel_launch(void* const* d_in, const int* in_sizes, int n_in,
                              void* d_out, int out_size, void* d_ws, size_t ws_size,
                              hipStream_t stream) {
  const int*   features = (const int*)  d_in[0];
  const int*   vocabs   = (const int*)  d_in[1];
  // d_in[2..5]: static topology (derived in-kernel)
  const float* eps      = (const float*)d_in[6];
  const float* emb_res  = (const float*)d_in[7];
  const float* emb_leaf = (const float*)d_in[8];
  const float* W_leaf   = (const float*)d_in[9];
  const float* b_leaf   = (const float*)d_in[10];
  const float* W_iou    = (const float*)d_in[11];
  const float* b_iou    = (const float*)d_in[12];
  const float* U_iou    = (const float*)d_in[13];
  const float* W_f      = (const float*)d_in[14];
  const float* b_f      = (const float*)d_in[15];
  const float* U_f      = (const float*)d_in[16];
  const float* Wm       = (const float*)d_in[17];
  const float* bm       = (const float*)d_in[18];
  const float* Wv       = (const float*)d_in[19];
  const float* bv       = (const float*)d_in[20];

  char* wsb = (char*)d_ws;
  bf16_t* hg  = (bf16_t*)wsb;                         // [NNODES][128] bf16
  float*  c2  = (float*)(wsb + 8388608);              // [NINT][128][2] f32 (child-pair c per parent)
  bf16_t* wxt = (bf16_t*)(wsb + 8388608 + 16777216);  // [600][128][4] bf16 wx table (i,o,u,f)
  float* out = (float*)d_out;

  k_leaf_table<<<133, 1024, 0, stream>>>(features, vocabs, emb_res, emb_leaf,
                                         W_iou, b_iou, W_f, b_f,
                                         W_leaf, b_leaf, wxt, hg, c2);
  k_levels<<<256, 512, 0, stream>>>(U_iou, U_f, features, wxt, hg, c2);
  k_tail<<<TREES, 512, 0, stream>>>(U_iou, U_f, features, wxt, hg, c2,
                                    Wm, bm, Wv, bv, eps, out);
}

// Round 19
// 70.243 us; speedup vs baseline: 1.4274x; 1.4274x over previous
//
#include <hip/hip_runtime.h>

#define TREES 32
#define NIPT  511
#define VLEAF 5000

typedef __bf16 bf16_t;
typedef bf16_t bf16x4 __attribute__((ext_vector_type(4)));
typedef bf16_t bf16x8 __attribute__((ext_vector_type(8)));
typedef float  f32x4  __attribute__((ext_vector_type(4)));

__device__ __forceinline__ float sigf(float x) { return 1.0f/(1.0f+__expf(-x)); }
__device__ __forceinline__ float tanh_fast(float x) { return 2.0f/(1.0f+__expf(-2.0f*x)) - 1.0f; }

__device__ __forceinline__ bf16x8 to_bf16x8(const float* p) {
  float4 a = *(const float4*)p;
  float4 b = *(const float4*)(p+4);
  bf16x8 r;
  r[0]=(bf16_t)a.x; r[1]=(bf16_t)a.y; r[2]=(bf16_t)a.z; r[3]=(bf16_t)a.w;
  r[4]=(bf16_t)b.x; r[5]=(bf16_t)b.y; r[6]=(bf16_t)b.z; r[7]=(bf16_t)b.w;
  return r;
}
__device__ __forceinline__ bf16x8 zero_bf16x8() {
  bf16x8 r;
  #pragma unroll
  for (int i=0;i<8;++i) r[i]=(bf16_t)0.0f;
  return r;
}

// ---- per-wave U fragments (fp32 source; L2-backed remat accepted — R9/R14-proven)
__device__ __forceinline__ void load_breg(const float* __restrict__ U_iou,
                                          const float* __restrict__ U_f,
                                          int cs, int lg, int col0, bf16x8 breg[8][4]) {
  #pragma unroll
  for (int gs=0; gs<8; ++gs) {
    int col = (gs>>1)*128 + cs*32 + (gs&1)*16 + col0;
    const float* src; int ld;
    if (col < 384) { src = U_iou + col; ld = 384; }
    else           { src = U_f + (col-384); ld = 128; }
    #pragma unroll
    for (int ks=0; ks<4; ++ks) {
      #pragma unroll
      for (int i=0;i<8;++i) breg[gs][ks][i] = (bf16_t)src[(ks*32 + lg*8 + i)*ld];
    }
  }
}

__device__ __forceinline__ void mfma8(const bf16x8 a[4], const bf16x8 breg[8][4], f32x4 acc[8]) {
  #pragma unroll
  for (int ks=0; ks<4; ++ks) {
    #pragma unroll
    for (int gs=0; gs<8; ++gs)
      acc[gs] = __builtin_amdgcn_mfma_f32_16x16x32_bf16(a[ks], breg[gs][ks], acc[gs], 0,0,0);
  }
}

// LSTM combine: acc gs = {i:0,1 | o:2,3 | u:4,5 | f:6,7}, rows 2pp,2pp+1 = children L,R
__device__ __forceinline__ void lstm_epi(const f32x4 acc[8], const bf16x4 w4[2][2],
                                         const float2 cp[2][2],
                                         float hn[2][2], float cn[2][2]) {
  #pragma unroll
  for (int pp=0; pp<2; ++pp) {
    #pragma unroll
    for (int s2=0; s2<2; ++s2) {
      float iv = acc[s2][2*pp]   + acc[s2][2*pp+1]   + (float)w4[pp][s2][0];
      float ov = acc[2+s2][2*pp] + acc[2+s2][2*pp+1] + (float)w4[pp][s2][1];
      float uv = acc[4+s2][2*pp] + acc[4+s2][2*pp+1] + (float)w4[pp][s2][2];
      float wf = (float)w4[pp][s2][3];
      float fl = sigf(acc[6+s2][2*pp]   + wf);
      float fr = sigf(acc[6+s2][2*pp+1] + wf);
      float cf = fl*cp[pp][s2].x + fr*cp[pp][s2].y;
      float c  = sigf(iv)*tanh_fast(uv) + cf;
      cn[pp][s2] = c;
      hn[pp][s2] = sigf(ov)*tanh_fast(c);
    }
  }
}

// =================== kernel 0: wx table (600 rows), B from L2 =================
// 19 blocks x 512 thr; block handles 32 rows (2 mtiles, one per rowgroup)
__global__ __launch_bounds__(512) void k_table(
    const float* __restrict__ emb_res,
    const float* __restrict__ W_iou, const float* __restrict__ b_iou,
    const float* __restrict__ W_f, const float* __restrict__ b_f,
    bf16_t* __restrict__ wxt)
{
  const int tid = threadIdx.x, wave = tid>>6, lane = tid&63;
  const int rg = wave>>2, cs = wave&3, lg = lane>>4, col0 = lane&15;
  int row0 = blockIdx.x*32 + rg*16;
  int rowA = row0 + (lane&15);
  if (rowA >= 600) rowA = 599;
  const float* ep = emb_res + (size_t)rowA*128 + lg*8;

  bf16x8 a[4];
  #pragma unroll
  for (int ks=0; ks<4; ++ks) a[ks] = to_bf16x8(ep + ks*32);

  f32x4 acc[8];
  #pragma unroll
  for (int j=0;j<8;++j) acc[j] = (f32x4){0.f,0.f,0.f,0.f};
  #pragma unroll
  for (int ks=0; ks<4; ++ks) {
    #pragma unroll
    for (int j=0; j<8; ++j) {
      int col = cs*128 + j*16 + col0;
      const float* src; int ld;
      if (col < 384) { src = W_iou + col; ld = 384; }
      else           { src = W_f + (col-384); ld = 128; }
      bf16x8 b;
      #pragma unroll
      for (int i=0;i<8;++i) b[i] = (bf16_t)src[(ks*32 + lg*8 + i)*ld];
      acc[j] = __builtin_amdgcn_mfma_f32_16x16x32_bf16(a[ks], b, acc[j], 0,0,0);
    }
  }
  #pragma unroll
  for (int j=0; j<8; ++j) {
    int hcol = j*16 + col0;
    int c = cs*128 + hcol;
    float bias = (c < 384) ? b_iou[c] : b_f[c-384];
    #pragma unroll
    for (int r=0; r<4; ++r) {
      int ci = row0 + lg*4 + r;
      if (ci >= 600) ci = 599;                 // duplicate writes carry identical data
      wxt[(size_t)ci*512 + hcol*4 + cs] = (bf16_t)(acc[j][r] + bias);
    }
  }
}

// =================== kernel 1: FUSED leaf + levels 1..6 =======================
// 256 blocks x 512 thr; leaf h/c live only in LDS; only order-6 goes global
__global__ __launch_bounds__(512, 2) void k_leaf_levels(
    const int* __restrict__ features, const int* __restrict__ vocabs,
    const float* __restrict__ emb_leaf, const float* __restrict__ b_leaf,
    const float* __restrict__ W_leaf,
    const float* __restrict__ U_iou, const float* __restrict__ U_f,
    const bf16_t* __restrict__ wxt, bf16_t* __restrict__ hg, float* __restrict__ c2)
{
  __shared__ __align__(16) bf16_t st_lh[64][136];   // leaf h
  __shared__ __align__(16) bf16_t st_lc[64][136];   // leaf c (bf16)
  __shared__ __align__(16) bf16_t st_h[48][136];    // level h
  __shared__ float st_c[48][132];                   // level c
  const int tid = threadIdx.x, wave = tid>>6, lane = tid&63;
  const int rg = wave>>2, cs = wave&3, lg = lane>>4, col0 = lane&15;
  const int blk = blockIdx.x, tree = blk>>3, b8 = blk&7;
  const int L0 = 511 + b8*64;                       // first leaf local index

  // ============ leaf phase: 64 leaves, B from W_leaf (L2), out -> LDS ========
  #pragma unroll
  for (int mi=0; mi<2; ++mi) {
    int mt = rg + mi*2;
    int jl = mt*16 + (lane&15);
    int nodeA = tree*1023 + L0 + jl;
    int kkA = vocabs[nodeA]-1;
    int featA = features[nodeA];
    const float* xp = emb_leaf + ((size_t)kkA*VLEAF + featA)*64;
    bf16x8 alo = to_bf16x8(xp + lg*8);
    bf16x8 ahi = to_bf16x8(xp + 32 + lg*8);

    f32x4 acc[6];
    #pragma unroll
    for (int j=0;j<6;++j) acc[j] = (f32x4){0.f,0.f,0.f,0.f};
    #pragma unroll
    for (int ks=0; ks<6; ++ks) {
      bf16x8 a = (ks == 2*kkA) ? alo : (ks == 2*kkA+1) ? ahi : zero_bf16x8();
      int k0 = ks*32 + lg*8;
      int kkb = k0>>6, kr = k0&63;
      #pragma unroll
      for (int g=0; g<3; ++g) {
        #pragma unroll
        for (int s=0; s<2; ++s) {
          int dcol = g*128 + cs*32 + s*16 + col0;
          int cm = (dcol < 128) ? dcol : dcol + 128;   // [gi,gg,go] from [gi,gf,gg,go]
          const float* wp = W_leaf + kkb*32768 + (size_t)kr*512 + cm;
          bf16x8 b;
          #pragma unroll
          for (int i=0;i<8;++i) b[i] = (bf16_t)wp[i*512];
          acc[g*2+s] = __builtin_amdgcn_mfma_f32_16x16x32_bf16(a, b, acc[g*2+s], 0,0,0);
        }
      }
    }
    #pragma unroll
    for (int r=0; r<4; ++r) {
      int j = mt*16 + lg*4 + r;
      int node = tree*1023 + L0 + j;
      int kk = vocabs[node]-1;
      const float* bl = b_leaf + kk*512;
      #pragma unroll
      for (int s=0; s<2; ++s) {
        int cc = cs*32 + s*16 + col0;
        float gi = acc[s][r]   + bl[cc];
        float gg = acc[2+s][r] + bl[256+cc];
        float go = acc[4+s][r] + bl[384+cc];
        float ck = sigf(gi)*tanh_fast(gg);
        float hk = sigf(go)*tanh_fast(ck);
        st_lc[j][cc] = (bf16_t)ck;
        st_lh[j][cc] = (bf16_t)hk;
      }
    }
  }

  bf16x8 breg[8][4];
  load_breg(U_iou, U_f, cs, lg, col0, breg);
  __syncthreads();

  // ============ n=1: A,c from leaf LDS; wx from table; out -> st rows 0..31 ==
  #pragma unroll
  for (int mi=0; mi<2; ++mi) {
    const int mt = rg + mi*2;
    int rr = lane&15;
    bf16x8 a[4];
    #pragma unroll
    for (int ks=0; ks<4; ++ks)
      a[ks] = *(const bf16x8*)(&st_lh[mt*16 + rr][ks*32 + lg*8]);

    bf16x4 w4[2][2]; float2 cp[2][2]; int pib[2];
    #pragma unroll
    for (int pp=0; pp<2; ++pp) {
      int pj = mt*8 + lg*2 + pp;
      pib[pp] = pj;
      int plocal = 255 + b8*32 + pj;
      int feat = features[tree*1023 + plocal];
      #pragma unroll
      for (int s2=0; s2<2; ++s2) {
        int hcol = cs*32 + s2*16 + col0;
        w4[pp][s2] = *(const bf16x4*)(wxt + (size_t)feat*512 + hcol*4);
        cp[pp][s2] = make_float2((float)st_lc[2*pj][hcol], (float)st_lc[2*pj+1][hcol]);
      }
    }

    f32x4 acc[8];
    #pragma unroll
    for (int gs=0; gs<8; ++gs) acc[gs] = (f32x4){0.f,0.f,0.f,0.f};
    mfma8(a, breg, acc);
    float hn[2][2], cn[2][2];
    lstm_epi(acc, w4, cp, hn, cn);
    #pragma unroll
    for (int pp=0; pp<2; ++pp) {
      #pragma unroll
      for (int s2=0; s2<2; ++s2) {
        int hcol = cs*32 + s2*16 + col0;
        st_c[pib[pp]][hcol] = cn[pp][s2];
        st_h[pib[pp]][hcol] = (bf16_t)hn[pp][s2];
      }
    }
  }
  __syncthreads();

  // ============ n=2: children = st rows 0..31; out -> st rows 32..47 =========
  {
    const int mt2 = rg;
    int rr = lane&15;
    int crow = mt2*16 + rr;
    bf16x8 a[4];
    #pragma unroll
    for (int ks=0; ks<4; ++ks)
      a[ks] = *(const bf16x8*)(&st_h[crow][ks*32 + lg*8]);

    bf16x4 w4[2][2]; float2 cp[2][2]; int pnode[2];
    #pragma unroll
    for (int pp=0; pp<2; ++pp) {
      int pj = mt2*8 + lg*2 + pp;                // [0,16)
      pnode[pp] = 32 + pj;
      int f2 = blk*16 + pj;
      int tr2 = f2>>7, lo = f2&127;
      int plocal = 127+lo;
      int feat = features[tr2*1023 + plocal];
      #pragma unroll
      for (int s2=0; s2<2; ++s2) {
        int hcol = cs*32 + s2*16 + col0;
        w4[pp][s2] = *(const bf16x4*)(wxt + (size_t)feat*512 + hcol*4);
        cp[pp][s2] = make_float2(st_c[2*pj][hcol], st_c[2*pj+1][hcol]);
      }
    }

    f32x4 acc[8];
    #pragma unroll
    for (int gs=0; gs<8; ++gs) acc[gs] = (f32x4){0.f,0.f,0.f,0.f};
    mfma8(a, breg, acc);
    float hn[2][2], cn[2][2];
    lstm_epi(acc, w4, cp, hn, cn);
    #pragma unroll
    for (int pp=0; pp<2; ++pp) {
      #pragma unroll
      for (int s2=0; s2<2; ++s2) {
        int hcol = cs*32 + s2*16 + col0;
        st_c[pnode[pp]][hcol] = cn[pp][s2];
        st_h[pnode[pp]][hcol] = (bf16_t)hn[pp][s2];
      }
    }
  }
  __syncthreads();

  // ============ n=3..6: rowgroup 0 only; st->st (li<3) or st->global (li=3) ==
  const int Pn_[4]   = {8, 4, 2, 1};
  const int cb_[4]   = {32, 0, 8, 12};     // child st row base
  const int ob_[4]   = {0, 8, 12, 0};      // out st row base (li<3)
  const int base_[4] = {63, 31, 15, 7};    // parent plocal base
  const int mul_[4]  = {8, 4, 2, 1};       // parents per block
  #pragma unroll
  for (int li=0; li<4; ++li) {
    if (rg == 0) {
      const int Pn = Pn_[li];
      int rr = lane&15;
      int r2 = (rr < 2*Pn) ? rr : 0;
      bf16x8 a[4];
      #pragma unroll
      for (int ks=0; ks<4; ++ks)
        a[ks] = *(const bf16x8*)(&st_h[cb_[li] + r2][ks*32 + lg*8]);

      bf16x4 w4[2][2]; float2 cp[2][2]; int pj[2], plocal[2];
      #pragma unroll
      for (int pp=0; pp<2; ++pp) {
        pj[pp] = lg*2 + pp;
        plocal[pp] = base_[li] + b8*mul_[li] + pj[pp];
        int feat = features[tree*1023 + plocal[pp]];
        int cr0 = cb_[li] + 2*pj[pp];
        #pragma unroll
        for (int s2=0; s2<2; ++s2) {
          int hcol = cs*32 + s2*16 + col0;
          w4[pp][s2] = *(const bf16x4*)(wxt + (size_t)feat*512 + hcol*4);
          cp[pp][s2] = make_float2(st_c[cr0][hcol], st_c[cr0+1][hcol]);
        }
      }

      f32x4 acc[8];
      #pragma unroll
      for (int gs=0; gs<8; ++gs) acc[gs] = (f32x4){0.f,0.f,0.f,0.f};
      mfma8(a, breg, acc);
      float hn[2][2], cn[2][2];
      lstm_epi(acc, w4, cp, hn, cn);
      #pragma unroll
      for (int pp=0; pp<2; ++pp) {
        if (pj[pp] < Pn) {
          #pragma unroll
          for (int s2=0; s2<2; ++s2) {
            int hcol = cs*32 + s2*16 + col0;
            if (li < 3) {
              st_c[ob_[li] + pj[pp]][hcol] = cn[pp][s2];
              st_h[ob_[li] + pj[pp]][hcol] = (bf16_t)hn[pp][s2];
            } else {
              // order-6 -> global (plocal = 7 + b8)
              int pl = plocal[pp] - 1;
              c2[((size_t)tree*511 + (pl>>1))*256 + hcol*2 + (pl&1)] = cn[pp][s2];
              hg[((size_t)tree*1023 + plocal[pp])*128 + hcol] = (bf16_t)hn[pp][s2];
            }
          }
        }
      }
    }
    __syncthreads();
  }
}

// =================== kernel 2: levels 7..9 + root head (R17 verbatim) =========
__global__ __launch_bounds__(512, 2) void k_tail(
    const float* __restrict__ U_iou, const float* __restrict__ U_f,
    const int* __restrict__ features, const bf16_t* __restrict__ wxt,
    bf16_t* __restrict__ hg, float* __restrict__ c2,
    const float* __restrict__ Wm, const float* __restrict__ bm,
    const float* __restrict__ Wv, const float* __restrict__ bv,
    const float* __restrict__ eps, float* __restrict__ out)
{
  __shared__ float hs[128];
  const int tid = threadIdx.x, wave = tid>>6, lane = tid&63;
  const int rg = wave>>2, cs = wave&3, lg = lane>>4, col0 = lane&15;
  const int tree = blockIdx.x;

  bf16x8 breg[8][4];
  load_breg(U_iou, U_f, cs, lg, col0, breg);

  const int Pn_[3]  = {4, 2, 1};
  const int chb_[3] = {7, 3, 1};     // child local base
  const int pb_[3]  = {3, 1, 0};     // parent local base
  #pragma unroll
  for (int li=0; li<3; ++li) {
    if (rg == 0) {
      const int Pn = Pn_[li];
      int rr = lane&15;
      int r2 = (rr < 2*Pn) ? rr : 0;
      const bf16_t* hp = hg + ((size_t)tree*1023 + chb_[li] + r2)*128 + lg*8;
      bf16x8 a[4];
      #pragma unroll
      for (int ks=0; ks<4; ++ks) a[ks] = *(const bf16x8*)(hp + ks*32);

      bf16x4 w4[2][2]; float2 cp[2][2]; int pj[2], plocal[2];
      #pragma unroll
      for (int pp=0; pp<2; ++pp) {
        pj[pp] = lg*2 + pp;
        plocal[pp] = pb_[li] + pj[pp];
        int pl_c = (plocal[pp] < 7) ? plocal[pp] : 6;
        int feat = features[tree*1023 + pl_c];
        size_t ci = (size_t)tree*511 + pl_c;
        #pragma unroll
        for (int s2=0; s2<2; ++s2) {
          int hcol = cs*32 + s2*16 + col0;
          w4[pp][s2] = *(const bf16x4*)(wxt + (size_t)feat*512 + hcol*4);
          cp[pp][s2] = *(const float2*)(c2 + ci*256 + hcol*2);
        }
      }

      f32x4 acc[8];
      #pragma unroll
      for (int gs=0; gs<8; ++gs) acc[gs] = (f32x4){0.f,0.f,0.f,0.f};
      mfma8(a, breg, acc);
      float hn[2][2], cn[2][2];
      lstm_epi(acc, w4, cp, hn, cn);
      #pragma unroll
      for (int pp=0; pp<2; ++pp) {
        if (pj[pp] < Pn) {
          #pragma unroll
          for (int s2=0; s2<2; ++s2) {
            int hcol = cs*32 + s2*16 + col0;
            if (li < 2) {
              int pl = plocal[pp] - 1;
              c2[((size_t)tree*511 + (pl>>1))*256 + hcol*2 + (pl&1)] = cn[pp][s2];
              hg[((size_t)tree*1023 + plocal[pp])*128 + hcol] = (bf16_t)hn[pp][s2];
            } else {
              hs[hcol] = hn[pp][s2];       // root h -> LDS only
            }
          }
        }
      }
    }
    __threadfence_block();
    __syncthreads();
  }

  // fused root head
  if (tid < 64) {
    const int j = tid;
    float am = 0.f, av = 0.f;
    #pragma unroll 4
    for (int i=0;i<128;++i) {
      float hv = hs[i];
      am += hv*Wm[i*64+j];
      av += hv*Wv[i*64+j];
    }
    float zm = am + bm[j];
    float zv = av + bv[j];
    int idx = tree*64 + j;
    out[idx]        = zm + eps[idx]*__expf(0.5f*zv);
    out[2048 + idx] = zm;
    out[4096 + idx] = zv;
  }
}

// =================== host launcher ============================================
extern "C" void kernel_launch(void* const* d_in, const int* in_sizes, int n_in,
                              void* d_out, int out_size, void* d_ws, size_t ws_size,
                              hipStream_t stream) {
  const int*   features = (const int*)  d_in[0];
  const int*   vocabs   = (const int*)  d_in[1];
  // d_in[2..5]: static topology (derived in-kernel)
  const float* eps      = (const float*)d_in[6];
  const float* emb_res  = (const float*)d_in[7];
  const float* emb_leaf = (const float*)d_in[8];
  const float* W_leaf   = (const float*)d_in[9];
  const float* b_leaf   = (const float*)d_in[10];
  const float* W_iou    = (const float*)d_in[11];
  const float* b_iou    = (const float*)d_in[12];
  const float* U_iou    = (const float*)d_in[13];
  const float* W_f      = (const float*)d_in[14];
  const float* b_f      = (const float*)d_in[15];
  const float* U_f      = (const float*)d_in[16];
  const float* Wm       = (const float*)d_in[17];
  const float* bm       = (const float*)d_in[18];
  const float* Wv       = (const float*)d_in[19];
  const float* bv       = (const float*)d_in[20];

  char* wsb = (char*)d_ws;
  bf16_t* hg  = (bf16_t*)wsb;                         // [NNODES][128] bf16 (orders 6-8 used)
  float*  c2  = (float*)(wsb + 8388608);              // [NINT][128][2] f32 (orders 6-8 used)
  bf16_t* wxt = (bf16_t*)(wsb + 8388608 + 16777216);  // [600][128][4] bf16 wx table (i,o,u,f)
  float* out = (float*)d_out;

  k_table<<<19, 512, 0, stream>>>(emb_res, W_iou, b_iou, W_f, b_f, wxt);
  k_leaf_levels<<<256, 512, 0, stream>>>(features, vocabs, emb_leaf, b_leaf, W_leaf,
                                         U_iou, U_f, wxt, hg, c2);
  k_tail<<<TREES, 512, 0, stream>>>(U_iou, U_f, features, wxt, hg, c2,
                                    Wm, bm, Wv, bv, eps, out);
}